// Round 15
// baseline (769.796 us; speedup 1.0000x reference)
//
#include <hip/hip_runtime.h>

// Sizes fixed by the problem: B=1, L=768, D=128, H=8, DH=16, N=6 layers.
#define L_SEQ 768
#define P_SZ  (L_SEQ * 128)   // 98304

// ---------------------------------------------------------------------------
// megaK: 480 blocks: ct = bid/48 (0..9), rt = bid%48 (16-row tiles).
// Folded stage: computes y1 = x + aPrev@W2^T + lob*ts and y2 = x + o@mw^T + mb
// for its 16 rows (W2 pre-accumulated by previous k2K with lo_w folded in),
// then x_cur = x + LN1(y1) + LN2(y2) into LDS; ct==0 writes x_cur back.
// Then the usual 16x64 GEMM producing a / tx / qkv slices.
// Blocks 0..128 also zero the NEXT layer's W2/ts accumulators.
// ---------------------------------------------------------------------------
__global__ __launch_bounds__(256, 3) void megaK(int first,
    const float* __restrict__ xprev, float* __restrict__ xcur,
    const float* __restrict__ aPrev, const float* __restrict__ oPrev,
    const float* __restrict__ W2rd, const float* __restrict__ tsrd,
    float* __restrict__ W2zero, float* __restrict__ tszero,
    const float* __restrict__ lobP, const float* __restrict__ mwP,
    const float* __restrict__ mbP,
    const float* __restrict__ g1, const float* __restrict__ b1,
    const float* __restrict__ g2, const float* __restrict__ b2,
    const float* __restrict__ lw, const float* __restrict__ lb,
    const float* __restrict__ ow, const float* __restrict__ ob,
    const float* __restrict__ qw, const float* __restrict__ qb,
    float* __restrict__ aOut, float* __restrict__ tx, float* __restrict__ qkv)
{
    __shared__ float Bs[64][132];
    __shared__ float Ap[16][132];
    __shared__ float OpAs[16][132];   // o-tile during stage, then x-tile (As)
    const int bid = blockIdx.x;
    const int tid = threadIdx.x;
    const int ct = bid / 48, rt = bid % 48;
    const int r0 = rt * 16;

    // zero next-layer accumulators (disjoint slices; done before k2K runs)
    if (bid < 128) {
        if (tid < 32)
            *(float4*)&W2zero[bid * 128 + tid * 4] = make_float4(0.f, 0.f, 0.f, 0.f);
    } else if (bid == 128) {
        if (tid < 32)
            *(float4*)&tszero[tid * 4] = make_float4(0.f, 0.f, 0.f, 0.f);
    }

    // weight selection + B-tile staging
    const float* W; const float* bias; float* outp; int ldC, colbase;
    if (ct < 2)      { W = lw; bias = lb; outp = aOut; ldC = 128; colbase = ct * 64; }
    else if (ct < 4) { W = ow; bias = ob; outp = tx;   ldC = 128; colbase = (ct - 2) * 64; }
    else             { W = qw; bias = qb; outp = qkv;  ldC = 384; colbase = (ct - 4) * 64; }
#pragma unroll
    for (int t = 0; t < 8; ++t) {
        int idx = tid + 256 * t;
        int brow = idx >> 5, f4 = idx & 31;
        *(float4*)&Bs[brow][f4 * 4] = *(const float4*)&W[(colbase + brow) * 128 + f4 * 4];
    }

    const int row = tid >> 4;          // 0..15
    const int cs  = (tid & 15) * 8;    // 0..120
    const int gr  = (r0 + row) * 128 + cs;

    if (first) {
        *(float4*)&OpAs[row][cs]     = *(const float4*)&xprev[gr];
        *(float4*)&OpAs[row][cs + 4] = *(const float4*)&xprev[gr + 4];
        __syncthreads();
    } else {
        // stage aPrev / oPrev tiles
#pragma unroll
        for (int t = 0; t < 2; ++t) {
            int idx = tid + 256 * t;          // 0..511
            int rr = idx >> 5, f4 = idx & 31;
            *(float4*)&Ap[rr][f4 * 4]   = *(const float4*)&aPrev[(r0 + rr) * 128 + f4 * 4];
            *(float4*)&OpAs[rr][f4 * 4] = *(const float4*)&oPrev[(r0 + rr) * 128 + f4 * 4];
        }
        __syncthreads();

        float y1v[8], y2v[8];
#pragma unroll
        for (int cc = 0; cc < 8; ++cc) { y1v[cc] = 0.f; y2v[cc] = 0.f; }
        for (int k4 = 0; k4 < 32; ++k4) {
            float4 av = *(const float4*)&Ap[row][k4 * 4];
            float4 ov = *(const float4*)&OpAs[row][k4 * 4];
#pragma unroll
            for (int cc = 0; cc < 8; ++cc) {
                int c = cs + cc;
                float4 wv = *(const float4*)&W2rd[c * 128 + k4 * 4];
                float4 mv = *(const float4*)&mwP[c * 128 + k4 * 4];
                y1v[cc] += av.x * wv.x + av.y * wv.y + av.z * wv.z + av.w * wv.w;
                y2v[cc] += ov.x * mv.x + ov.y * mv.y + ov.z * mv.z + ov.w * mv.w;
            }
        }
        float4 xv0 = *(const float4*)&xprev[gr];
        float4 xv1 = *(const float4*)&xprev[gr + 4];
        float xvv[8] = {xv0.x, xv0.y, xv0.z, xv0.w, xv1.x, xv1.y, xv1.z, xv1.w};
        float s1 = 0.f, s2 = 0.f;
#pragma unroll
        for (int cc = 0; cc < 8; ++cc) {
            int c = cs + cc;
            y1v[cc] += xvv[cc] + lobP[c] * tsrd[c];
            y2v[cc] += xvv[cc] + mbP[c];
            s1 += y1v[cc]; s2 += y2v[cc];
        }
#pragma unroll
        for (int mm = 1; mm < 16; mm <<= 1) { s1 += __shfl_xor(s1, mm); s2 += __shfl_xor(s2, mm); }
        const float mu1 = s1 * (1.0f / 128.0f), mu2 = s2 * (1.0f / 128.0f);
        float q1 = 0.f, q2 = 0.f;
#pragma unroll
        for (int cc = 0; cc < 8; ++cc) {
            float d1 = y1v[cc] - mu1; q1 += d1 * d1;
            float d2 = y2v[cc] - mu2; q2 += d2 * d2;
        }
#pragma unroll
        for (int mm = 1; mm < 16; mm <<= 1) { q1 += __shfl_xor(q1, mm); q2 += __shfl_xor(q2, mm); }
        const float rs1 = rsqrtf(q1 * (1.0f / 128.0f) + 1e-5f);
        const float rs2 = rsqrtf(q2 * (1.0f / 128.0f) + 1e-5f);
        float res[8];
#pragma unroll
        for (int cc = 0; cc < 8; ++cc) {
            int c = cs + cc;
            res[cc] = xvv[cc] + (y1v[cc] - mu1) * rs1 * g1[c] + b1[c]
                              + (y2v[cc] - mu2) * rs2 * g2[c] + b2[c];
        }
        __syncthreads();                 // all reads of Ap/OpAs complete
        *(float4*)&OpAs[row][cs]     = make_float4(res[0], res[1], res[2], res[3]);
        *(float4*)&OpAs[row][cs + 4] = make_float4(res[4], res[5], res[6], res[7]);
        if (ct == 0) {
            *(float4*)&xcur[gr]     = make_float4(res[0], res[1], res[2], res[3]);
            *(float4*)&xcur[gr + 4] = make_float4(res[4], res[5], res[6], res[7]);
        }
        __syncthreads();
    }

    // GEMM: 16 rows x 64 cols
    const int rg = tid >> 4, ng = tid & 15;
    float accs[4];
#pragma unroll
    for (int c = 0; c < 4; ++c) accs[c] = bias[colbase + ng + 16 * c];
#pragma unroll 8
    for (int kk = 0; kk < 32; ++kk) {
        float4 a1 = *(const float4*)&OpAs[rg][kk * 4];
#pragma unroll
        for (int c = 0; c < 4; ++c) {
            float4 b = *(const float4*)&Bs[ng + 16 * c][kk * 4];
            accs[c] += a1.x * b.x + a1.y * b.y + a1.z * b.z + a1.w * b.w;
        }
    }
    const int r = r0 + rg;
#pragma unroll
    for (int c = 0; c < 4; ++c)
        outp[r * ldC + colbase + ng + 16 * c] = accs[c];
}

// ---------------------------------------------------------------------------
// k2K: attention (blocks 0..383: h = bid/48, 16-row chunks, 16 partitions —
// round-12 verified body) + atat blocks (384..415: jc 0..7 over 96 j-rows,
// ot 0..3) which atomically accumulate W2 += lo_w .* (a^T tx) and ts.
// ---------------------------------------------------------------------------
__global__ __launch_bounds__(256, 4) void k2K(const float* __restrict__ qkv,
    const float* __restrict__ a_, const float* __restrict__ tx_,
    float* __restrict__ o_, float* __restrict__ W2acc, float* __restrict__ tsg,
    const float* __restrict__ lo_w)
{
    __shared__ __align__(16) char smem[49152];
    const int bid = blockIdx.x;
    const int tid = threadIdx.x;
    if (bid < 384) {
        float* Ks = (float*)smem;            // [192][20]
        float* Vs = Ks + 192 * 20;           // [192][20]
        float* sm = Vs + 192 * 20;           // [16][16]
        float* sl = sm + 256;                // [16][16]
        float* sacc = sl + 256;              // [16][16][16]
        const int h = bid / 48;
        const int ch = bid % 48;
        const int r = tid & 15;
        const int part = tid >> 4;
        const int qi = ch * 16 + r;

        float q[16];
        {
            const float4* qr = (const float4*)(qkv + qi * 384 + h * 16);
#pragma unroll
            for (int s = 0; s < 4; ++s) {
                float4 v = qr[s];
                q[s * 4 + 0] = v.x; q[s * 4 + 1] = v.y;
                q[s * 4 + 2] = v.z; q[s * 4 + 3] = v.w;
            }
        }
        float m = -1e30f, l = 0.0f;
        float acc[16];
#pragma unroll
        for (int d = 0; d < 16; ++d) acc[d] = 0.0f;

        for (int s = 0; s < 4; ++s) {   // 4 staging passes of 192 keys
            __syncthreads();
#pragma unroll
            for (int t = 0; t < 3; ++t) {
                int idx = tid + 256 * t;       // 0..767
                int row = idx >> 2, d4 = idx & 3;
                int j = s * 192 + row;
                *(float4*)&Ks[row * 20 + d4 * 4] =
                    *(const float4*)&qkv[j * 384 + 128 + h * 16 + d4 * 4];
                *(float4*)&Vs[row * 20 + d4 * 4] =
                    *(const float4*)&qkv[j * 384 + 256 + h * 16 + d4 * 4];
            }
            __syncthreads();
            const int tb = part * 12;
            for (int jj = 0; jj < 12; ++jj) {
                int t = tb + jj;
                float sc = 0.0f;
#pragma unroll
                for (int d = 0; d < 16; ++d) sc += q[d] * Ks[t * 20 + d];
                sc *= 0.25f;
                if (sc > m + 8.0f) {            // defer-max rescale (rare)
                    float f = __expf(m - sc);   // 0 when m == -1e30
                    l *= f;
#pragma unroll
                    for (int d = 0; d < 16; ++d) acc[d] *= f;
                    m = sc;
                }
                float p = __expf(sc - m);
                l += p;
#pragma unroll
                for (int d = 0; d < 16; ++d) acc[d] += p * Vs[t * 20 + d];
            }
        }
        sm[part * 16 + r] = m;
        sl[part * 16 + r] = l;
#pragma unroll
        for (int d = 0; d < 16; ++d) sacc[(part * 16 + r) * 16 + d] = acc[d];
        __syncthreads();

        // merge: each thread owns (row, d)
        const int row = tid >> 4, d = tid & 15;
        float M = sm[row];
#pragma unroll
        for (int p = 1; p < 16; ++p) M = fmaxf(M, sm[p * 16 + row]);
        float L = 0.0f, o = 0.0f;
#pragma unroll
        for (int p = 0; p < 16; ++p) {
            float f = __expf(sm[p * 16 + row] - M);
            L += sl[p * 16 + row] * f;
            o += sacc[(p * 16 + row) * 16 + d] * f;
        }
        o_[(ch * 16 + row) * 128 + h * 16 + d] = o / L;
    } else {
        // ---- atat: jc over 96 rows in two halves; atomic accumulate ----
        const int idx0 = bid - 384;          // 0..31
        const int jc = idx0 >> 2, ot = idx0 & 3;
        float* As  = (float*)smem;           // [48][128]
        float* Ts  = As + 48 * 128;          // [48][32]
        float* red = Ts + 48 * 32;           // [256]
        const int c4 = tid & 31, owt = tid >> 5;
        float accm[4][4] = {};
        float tsl = 0.0f;
        for (int half = 0; half < 2; ++half) {
            const int j0 = jc * 96 + half * 48;
            __syncthreads();
#pragma unroll
            for (int t = 0; t < 6; ++t) {
                int ix = tid + 256 * t;      // 0..1535
                int jj = ix >> 5, f4 = ix & 31;
                *(float4*)&As[jj * 128 + f4 * 4] =
                    *(const float4*)&a_[(j0 + jj) * 128 + f4 * 4];
            }
#pragma unroll
            for (int t = 0; t < 2; ++t) {
                int ix = tid + 256 * t;
                if (ix < 384) {
                    int jj = ix >> 3, f4 = ix & 7;
                    *(float4*)&Ts[jj * 32 + f4 * 4] =
                        *(const float4*)&tx_[(j0 + jj) * 128 + ot * 32 + f4 * 4];
                }
            }
            __syncthreads();
#pragma unroll 4
            for (int jj = 0; jj < 48; ++jj) {
                float4 av = *(const float4*)&As[jj * 128 + c4 * 4];
                float4 tv = *(const float4*)&Ts[jj * 32 + owt * 4];
                float avv[4] = {av.x, av.y, av.z, av.w};
                float tvv[4] = {tv.x, tv.y, tv.z, tv.w};
#pragma unroll
                for (int oi = 0; oi < 4; ++oi)
#pragma unroll
                    for (int ci = 0; ci < 4; ++ci)
                        accm[oi][ci] += avv[ci] * tvv[oi];
            }
            {   // tsum partial for this half
                const int o = tid & 31, g = tid >> 5;
                float s = 0.0f;
#pragma unroll
                for (int jj = 0; jj < 6; ++jj) s += Ts[(g * 6 + jj) * 32 + o];
                tsl += s;
            }
        }
        // atomic accumulate W2 = lo_w .* M (linearity: fold lo_w per partial)
#pragma unroll
        for (int oi = 0; oi < 4; ++oi) {
            int o = ot * 32 + owt * 4 + oi;
            const float* lwr = &lo_w[o * 128 + c4 * 4];
            float* w2r = &W2acc[o * 128 + c4 * 4];
            unsafeAtomicAdd(&w2r[0], lwr[0] * accm[oi][0]);
            unsafeAtomicAdd(&w2r[1], lwr[1] * accm[oi][1]);
            unsafeAtomicAdd(&w2r[2], lwr[2] * accm[oi][2]);
            unsafeAtomicAdd(&w2r[3], lwr[3] * accm[oi][3]);
        }
        __syncthreads();
        {
            const int o = tid & 31, g = tid >> 5;
            red[g * 32 + o] = tsl;
        }
        __syncthreads();
        if (tid < 32) {
            float s = 0.0f;
#pragma unroll
            for (int g = 0; g < 8; ++g) s += red[g * 32 + tid];
            unsafeAtomicAdd(&tsg[ot * 32 + tid], s);
        }
    }
}

// ---------------------------------------------------------------------------
// finK: 96 blocks: ct = bid/48, rt = bid%48. Folded stage (y1/y2 from
// aPrev/oPrev/W2/mw of layer 5) then out = x6 @ l1_w^T + l1_b.
// ---------------------------------------------------------------------------
__global__ __launch_bounds__(256, 3) void finK(
    const float* __restrict__ xprev,
    const float* __restrict__ aPrev, const float* __restrict__ oPrev,
    const float* __restrict__ W2rd, const float* __restrict__ tsrd,
    const float* __restrict__ lobP, const float* __restrict__ mwP,
    const float* __restrict__ mbP,
    const float* __restrict__ g1, const float* __restrict__ b1,
    const float* __restrict__ g2, const float* __restrict__ b2,
    const float* __restrict__ w, const float* __restrict__ bias,
    float* __restrict__ outp)
{
    __shared__ float Bs[64][132];
    __shared__ float Ap[16][132];
    __shared__ float OpAs[16][132];
    const int bid = blockIdx.x;
    const int tid = threadIdx.x;
    const int ct = bid / 48, rt = bid % 48;
    const int r0 = rt * 16;
    const int colbase = ct * 64;
#pragma unroll
    for (int t = 0; t < 8; ++t) {
        int idx = tid + 256 * t;
        int brow = idx >> 5, f4 = idx & 31;
        *(float4*)&Bs[brow][f4 * 4] = *(const float4*)&w[(colbase + brow) * 128 + f4 * 4];
    }
    const int row = tid >> 4;
    const int cs  = (tid & 15) * 8;
    const int gr  = (r0 + row) * 128 + cs;
#pragma unroll
    for (int t = 0; t < 2; ++t) {
        int idx = tid + 256 * t;
        int rr = idx >> 5, f4 = idx & 31;
        *(float4*)&Ap[rr][f4 * 4]   = *(const float4*)&aPrev[(r0 + rr) * 128 + f4 * 4];
        *(float4*)&OpAs[rr][f4 * 4] = *(const float4*)&oPrev[(r0 + rr) * 128 + f4 * 4];
    }
    __syncthreads();
    float y1v[8], y2v[8];
#pragma unroll
    for (int cc = 0; cc < 8; ++cc) { y1v[cc] = 0.f; y2v[cc] = 0.f; }
    for (int k4 = 0; k4 < 32; ++k4) {
        float4 av = *(const float4*)&Ap[row][k4 * 4];
        float4 ov = *(const float4*)&OpAs[row][k4 * 4];
#pragma unroll
        for (int cc = 0; cc < 8; ++cc) {
            int c = cs + cc;
            float4 wv = *(const float4*)&W2rd[c * 128 + k4 * 4];
            float4 mv = *(const float4*)&mwP[c * 128 + k4 * 4];
            y1v[cc] += av.x * wv.x + av.y * wv.y + av.z * wv.z + av.w * wv.w;
            y2v[cc] += ov.x * mv.x + ov.y * mv.y + ov.z * mv.z + ov.w * mv.w;
        }
    }
    float4 xv0 = *(const float4*)&xprev[gr];
    float4 xv1 = *(const float4*)&xprev[gr + 4];
    float xvv[8] = {xv0.x, xv0.y, xv0.z, xv0.w, xv1.x, xv1.y, xv1.z, xv1.w};
    float s1 = 0.f, s2 = 0.f;
#pragma unroll
    for (int cc = 0; cc < 8; ++cc) {
        int c = cs + cc;
        y1v[cc] += xvv[cc] + lobP[c] * tsrd[c];
        y2v[cc] += xvv[cc] + mbP[c];
        s1 += y1v[cc]; s2 += y2v[cc];
    }
#pragma unroll
    for (int mm = 1; mm < 16; mm <<= 1) { s1 += __shfl_xor(s1, mm); s2 += __shfl_xor(s2, mm); }
    const float mu1 = s1 * (1.0f / 128.0f), mu2 = s2 * (1.0f / 128.0f);
    float q1 = 0.f, q2 = 0.f;
#pragma unroll
    for (int cc = 0; cc < 8; ++cc) {
        float d1 = y1v[cc] - mu1; q1 += d1 * d1;
        float d2 = y2v[cc] - mu2; q2 += d2 * d2;
    }
#pragma unroll
    for (int mm = 1; mm < 16; mm <<= 1) { q1 += __shfl_xor(q1, mm); q2 += __shfl_xor(q2, mm); }
    const float rs1 = rsqrtf(q1 * (1.0f / 128.0f) + 1e-5f);
    const float rs2 = rsqrtf(q2 * (1.0f / 128.0f) + 1e-5f);
    float res[8];
#pragma unroll
    for (int cc = 0; cc < 8; ++cc) {
        int c = cs + cc;
        res[cc] = xvv[cc] + (y1v[cc] - mu1) * rs1 * g1[c] + b1[c]
                          + (y2v[cc] - mu2) * rs2 * g2[c] + b2[c];
    }
    __syncthreads();
    *(float4*)&OpAs[row][cs]     = make_float4(res[0], res[1], res[2], res[3]);
    *(float4*)&OpAs[row][cs + 4] = make_float4(res[4], res[5], res[6], res[7]);
    __syncthreads();

    const int rg = tid >> 4, ng = tid & 15;
    float accs[4];
#pragma unroll
    for (int c = 0; c < 4; ++c) accs[c] = bias[colbase + ng + 16 * c];
#pragma unroll 8
    for (int kk = 0; kk < 32; ++kk) {
        float4 a1 = *(const float4*)&OpAs[rg][kk * 4];
#pragma unroll
        for (int c = 0; c < 4; ++c) {
            float4 b = *(const float4*)&Bs[ng + 16 * c][kk * 4];
            accs[c] += a1.x * b.x + a1.y * b.y + a1.z * b.z + a1.w * b.w;
        }
    }
    const int r = r0 + rg;
#pragma unroll
    for (int c = 0; c < 4; ++c)
        outp[r * 128 + colbase + ng + 16 * c] = accs[c];
}

// ---------------------------------------------------------------------------
extern "C" void kernel_launch(void* const* d_in, const int* in_sizes, int n_in,
                              void* d_out, int out_size, void* d_ws, size_t ws_size,
                              hipStream_t stream)
{
    const float* x_in      = (const float*)d_in[0];
    const float* cop_l_w   = (const float*)d_in[1];
    const float* cop_l_b   = (const float*)d_in[2];
    const float* cop_lo_w  = (const float*)d_in[3];
    const float* cop_lo_b  = (const float*)d_in[4];
    const float* cop_out_w = (const float*)d_in[5];
    const float* cop_out_b = (const float*)d_in[6];
    const float* cop_ln_g  = (const float*)d_in[7];
    const float* cop_ln_b  = (const float*)d_in[8];
    const float* qkv_w     = (const float*)d_in[9];
    const float* qkv_b     = (const float*)d_in[10];
    const float* mha_out_w = (const float*)d_in[11];
    const float* mha_out_b = (const float*)d_in[12];
    const float* mha_ln_g  = (const float*)d_in[13];
    const float* mha_ln_b  = (const float*)d_in[14];
    const float* l1_w      = (const float*)d_in[15];
    const float* l1_b      = (const float*)d_in[16];

    float* ws = (float*)d_ws;
    float* xA   = ws + 0 * P_SZ;
    float* xB   = ws + 1 * P_SZ;
    float* aA   = ws + 2 * P_SZ;
    float* aB   = ws + 3 * P_SZ;
    float* tx_  = ws + 4 * P_SZ;
    float* qkv_ = ws + 5 * P_SZ;            // 3*P_SZ floats
    float* o_   = ws + 8 * P_SZ;
    float* W2A  = ws + 9 * P_SZ;            // 16384
    float* W2B  = W2A + 16384;              // 16384
    float* tsA  = W2B + 16384;              // 128
    float* tsB  = tsA + 128;                // 128

    const float* xc = x_in;

    for (int i = 0; i < 6; ++i) {
        const float* lw  = cop_l_w   + i * 16384;
        const float* lb  = cop_l_b   + i * 128;
        const float* low = cop_lo_w  + i * 16384;
        const float* ow  = cop_out_w + i * 16384;
        const float* ob  = cop_out_b + i * 128;
        const float* qw  = qkv_w     + i * 49152;
        const float* qb  = qkv_b     + i * 384;

        float* aCur = (i & 1) ? aB : aA;
        const float* aPrv = (i & 1) ? aA : aB;
        float* W2cur = (i & 1) ? W2B : W2A;       // zeroed now, filled by k2K(i)
        const float* W2prv = (i & 1) ? W2A : W2B; // layer i-1's accumulated W2
        float* tscur = (i & 1) ? tsB : tsA;
        const float* tsprv = (i & 1) ? tsA : tsB;

        if (i == 0) {
            megaK<<<480, 256, 0, stream>>>(1, x_in, nullptr, nullptr, nullptr,
                                           nullptr, nullptr, W2cur, tscur,
                                           nullptr, nullptr, nullptr,
                                           nullptr, nullptr, nullptr, nullptr,
                                           lw, lb, ow, ob, qw, qb,
                                           aCur, tx_, qkv_);
        } else {
            float* xn = (i & 1) ? xB : xA;
            megaK<<<480, 256, 0, stream>>>(0, xc, xn, aPrv, o_,
                                           W2prv, tsprv, W2cur, tscur,
                                           cop_lo_b + (i - 1) * 128,
                                           mha_out_w + (i - 1) * 16384,
                                           mha_out_b + (i - 1) * 128,
                                           cop_ln_g + (i - 1) * 128,
                                           cop_ln_b + (i - 1) * 128,
                                           mha_ln_g + (i - 1) * 128,
                                           mha_ln_b + (i - 1) * 128,
                                           lw, lb, ow, ob, qw, qb,
                                           aCur, tx_, qkv_);
            xc = xn;
        }
        k2K<<<416, 256, 0, stream>>>(qkv_, aCur, tx_, o_, W2cur, tscur, low);
    }

    // final: layer 5 outputs are in aB (5&1=1), W2B, tsB, o_
    finK<<<96, 256, 0, stream>>>(xc, aB, o_, W2B, tsB,
                                 cop_lo_b + 5 * 128,
                                 mha_out_w + 5 * 16384,
                                 mha_out_b + 5 * 128,
                                 cop_ln_g + 5 * 128, cop_ln_b + 5 * 128,
                                 mha_ln_g + 5 * 128, mha_ln_b + 5 * 128,
                                 l1_w, l1_b, (float*)d_out);
}

// Round 16
// 256.136 us; speedup vs baseline: 3.0054x; 3.0054x over previous
//
#include <hip/hip_runtime.h>

// Sizes fixed by the problem: B=1, L=768, D=128, H=8, DH=16, N=6 layers.
#define L_SEQ 768
#define P_SZ  (L_SEQ * 128)   // 98304

// ---------------------------------------------------------------------------
// Stage a 16-row x 128-col tile of the residual stream into As.
// first: tile = xprev rows.  else: tile = xprev + LN1(y1) + LN2(y2)
// (16 threads/row, 8 cols each, shfl reduce).  writeback: also store to xcur.
// ---------------------------------------------------------------------------
__device__ __forceinline__ void stage16(int tid, int r0, bool first,
    bool writeback, const float* xprev, const float* y1, const float* y2,
    const float* g1, const float* b1, const float* g2, const float* b2,
    float* xcur, float (*As)[132])
{
    const int row = tid >> 4;          // 0..15
    const int cs  = (tid & 15) * 8;    // 0..120
    const int gr  = (r0 + row) * 128 + cs;
    if (first) {
#pragma unroll
        for (int u = 0; u < 2; ++u)
            *(float4*)&As[row][cs + 4 * u] = *(const float4*)&xprev[gr + 4 * u];
        return;
    }
    float4 v1[2], v2[2];
    float s1 = 0.0f, s2 = 0.0f;
#pragma unroll
    for (int u = 0; u < 2; ++u) {
        v1[u] = *(const float4*)&y1[gr + 4 * u];
        v2[u] = *(const float4*)&y2[gr + 4 * u];
        s1 += v1[u].x + v1[u].y + v1[u].z + v1[u].w;
        s2 += v2[u].x + v2[u].y + v2[u].z + v2[u].w;
    }
#pragma unroll
    for (int m = 1; m < 16; m <<= 1) { s1 += __shfl_xor(s1, m); s2 += __shfl_xor(s2, m); }
    const float mu1 = s1 * (1.0f / 128.0f), mu2 = s2 * (1.0f / 128.0f);
    float q1 = 0.0f, q2 = 0.0f;
#pragma unroll
    for (int u = 0; u < 2; ++u) {
        float d;
        d = v1[u].x - mu1; q1 += d * d;  d = v1[u].y - mu1; q1 += d * d;
        d = v1[u].z - mu1; q1 += d * d;  d = v1[u].w - mu1; q1 += d * d;
        d = v2[u].x - mu2; q2 += d * d;  d = v2[u].y - mu2; q2 += d * d;
        d = v2[u].z - mu2; q2 += d * d;  d = v2[u].w - mu2; q2 += d * d;
    }
#pragma unroll
    for (int m = 1; m < 16; m <<= 1) { q1 += __shfl_xor(q1, m); q2 += __shfl_xor(q2, m); }
    const float rs1 = rsqrtf(q1 * (1.0f / 128.0f) + 1e-5f);
    const float rs2 = rsqrtf(q2 * (1.0f / 128.0f) + 1e-5f);
#pragma unroll
    for (int u = 0; u < 2; ++u) {
        float4 ga = *(const float4*)&g1[cs + 4 * u];
        float4 ba = *(const float4*)&b1[cs + 4 * u];
        float4 gb = *(const float4*)&g2[cs + 4 * u];
        float4 bb = *(const float4*)&b2[cs + 4 * u];
        float4 xv = *(const float4*)&xprev[gr + 4 * u];
        float4 o;
        o.x = xv.x + (v1[u].x - mu1) * rs1 * ga.x + ba.x + (v2[u].x - mu2) * rs2 * gb.x + bb.x;
        o.y = xv.y + (v1[u].y - mu1) * rs1 * ga.y + ba.y + (v2[u].y - mu2) * rs2 * gb.y + bb.y;
        o.z = xv.z + (v1[u].z - mu1) * rs1 * ga.z + ba.z + (v2[u].z - mu2) * rs2 * gb.z + bb.z;
        o.w = xv.w + (v1[u].w - mu1) * rs1 * ga.w + ba.w + (v2[u].w - mu2) * rs2 * gb.w + bb.w;
        *(float4*)&As[row][cs + 4 * u] = o;
        if (writeback) *(float4*)&xcur[gr + 4 * u] = o;
    }
}

// ---------------------------------------------------------------------------
// megaK: 480 blocks: ct = bid/48 (0..9), rt = bid%48 (16-row tiles).
// ---------------------------------------------------------------------------
__global__ __launch_bounds__(256, 4) void megaK(int first,
    const float* __restrict__ xprev, const float* __restrict__ y1,
    const float* __restrict__ y2, float* __restrict__ xcur,
    const float* __restrict__ g1, const float* __restrict__ b1,
    const float* __restrict__ g2, const float* __restrict__ b2,
    const float* __restrict__ lw, const float* __restrict__ lb,
    const float* __restrict__ ow, const float* __restrict__ ob,
    const float* __restrict__ qw, const float* __restrict__ qb,
    float* __restrict__ a, float* __restrict__ tx, float* __restrict__ qkv)
{
    __shared__ float Bs[64][132];
    __shared__ float As[16][132];
    const int bid = blockIdx.x;
    const int tid = threadIdx.x;
    const int ct = bid / 48, rt = bid % 48;
    const int r0 = rt * 16;
    stage16(tid, r0, first != 0, (!first && ct == 0), xprev, y1, y2,
            g1, b1, g2, b2, xcur, As);
    const float* W; const float* bias; float* outp; int ldC, colbase;
    if (ct < 2)      { W = lw; bias = lb; outp = a;   ldC = 128; colbase = ct * 64; }
    else if (ct < 4) { W = ow; bias = ob; outp = tx;  ldC = 128; colbase = (ct - 2) * 64; }
    else             { W = qw; bias = qb; outp = qkv; ldC = 384; colbase = (ct - 4) * 64; }
#pragma unroll
    for (int t = 0; t < 8; ++t) {
        int idx = tid + 256 * t;
        int brow = idx >> 5, f4 = idx & 31;
        *(float4*)&Bs[brow][f4 * 4] = *(const float4*)&W[(colbase + brow) * 128 + f4 * 4];
    }
    __syncthreads();
    const int rg = tid >> 4, ng = tid & 15;
    float accs[4];
#pragma unroll
    for (int c = 0; c < 4; ++c) accs[c] = bias[colbase + ng + 16 * c];
#pragma unroll 8
    for (int kk = 0; kk < 32; ++kk) {
        float4 a1 = *(const float4*)&As[rg][kk * 4];
#pragma unroll
        for (int c = 0; c < 4; ++c) {
            float4 b = *(const float4*)&Bs[ng + 16 * c][kk * 4];
            accs[c] += a1.x * b.x + a1.y * b.y + a1.z * b.z + a1.w * b.w;
        }
    }
    const int r = r0 + rg;
#pragma unroll
    for (int c = 0; c < 4; ++c)
        outp[r * ldC + colbase + ng + 16 * c] = accs[c];
}

// ---------------------------------------------------------------------------
// k2K: attention (blocks 0..383: h = bid/48, 16-row chunks, 16 partitions,
// defer-max) + atat/tsum partials (blocks 384..415: jc 0..7 over 96 j-rows,
// ot 0..3).
// ---------------------------------------------------------------------------
__global__ __launch_bounds__(256, 4) void k2K(const float* __restrict__ qkv,
    const float* __restrict__ a_, const float* __restrict__ tx_,
    float* __restrict__ o_, float* __restrict__ Mpart, float* __restrict__ tspart)
{
    __shared__ __align__(16) char smem[49152];
    const int bid = blockIdx.x;
    const int tid = threadIdx.x;
    if (bid < 384) {
        float* Ks = (float*)smem;            // [192][20]
        float* Vs = Ks + 192 * 20;           // [192][20]
        float* sm = Vs + 192 * 20;           // [16][16]
        float* sl = sm + 256;                // [16][16]
        float* sacc = sl + 256;              // [16][16][16]
        const int h = bid / 48;
        const int ch = bid % 48;
        const int r = tid & 15;
        const int part = tid >> 4;
        const int qi = ch * 16 + r;

        float q[16];
        {
            const float4* qr = (const float4*)(qkv + qi * 384 + h * 16);
#pragma unroll
            for (int s = 0; s < 4; ++s) {
                float4 v = qr[s];
                q[s * 4 + 0] = v.x; q[s * 4 + 1] = v.y;
                q[s * 4 + 2] = v.z; q[s * 4 + 3] = v.w;
            }
        }
        float m = -1e30f, l = 0.0f;
        float acc[16];
#pragma unroll
        for (int d = 0; d < 16; ++d) acc[d] = 0.0f;

        for (int s = 0; s < 4; ++s) {   // 4 staging passes of 192 keys
            __syncthreads();
#pragma unroll
            for (int t = 0; t < 3; ++t) {
                int idx = tid + 256 * t;       // 0..767
                int row = idx >> 2, d4 = idx & 3;
                int j = s * 192 + row;
                *(float4*)&Ks[row * 20 + d4 * 4] =
                    *(const float4*)&qkv[j * 384 + 128 + h * 16 + d4 * 4];
                *(float4*)&Vs[row * 20 + d4 * 4] =
                    *(const float4*)&qkv[j * 384 + 256 + h * 16 + d4 * 4];
            }
            __syncthreads();
            const int tb = part * 12;
            for (int jj = 0; jj < 12; ++jj) {
                int t = tb + jj;
                float sc = 0.0f;
#pragma unroll
                for (int d = 0; d < 16; ++d) sc += q[d] * Ks[t * 20 + d];
                sc *= 0.25f;
                if (sc > m + 8.0f) {            // defer-max rescale (rare)
                    float f = __expf(m - sc);   // 0 when m == -1e30
                    l *= f;
#pragma unroll
                    for (int d = 0; d < 16; ++d) acc[d] *= f;
                    m = sc;
                }
                float p = __expf(sc - m);
                l += p;
#pragma unroll
                for (int d = 0; d < 16; ++d) acc[d] += p * Vs[t * 20 + d];
            }
        }
        sm[part * 16 + r] = m;
        sl[part * 16 + r] = l;
#pragma unroll
        for (int d = 0; d < 16; ++d) sacc[(part * 16 + r) * 16 + d] = acc[d];
        __syncthreads();

        // merge: each thread owns (row, d)
        const int row = tid >> 4, d = tid & 15;
        float M = sm[row];
#pragma unroll
        for (int p = 1; p < 16; ++p) M = fmaxf(M, sm[p * 16 + row]);
        float L = 0.0f, o = 0.0f;
#pragma unroll
        for (int p = 0; p < 16; ++p) {
            float f = __expf(sm[p * 16 + row] - M);
            L += sl[p * 16 + row] * f;
            o += sacc[(p * 16 + row) * 16 + d] * f;
        }
        o_[(ch * 16 + row) * 128 + h * 16 + d] = o / L;
    } else {
        // ---- atat partial + tsum partial: jc over 96 rows in two halves ----
        const int idx0 = bid - 384;          // 0..31
        const int jc = idx0 >> 2, ot = idx0 & 3;
        float* As  = (float*)smem;           // [48][128]
        float* Ts  = As + 48 * 128;          // [48][32]
        float* red = Ts + 48 * 32;           // [256]
        const int c4 = tid & 31, owt = tid >> 5;
        float accm[4][4] = {};
        float tsacc = 0.0f;
        for (int half = 0; half < 2; ++half) {
            const int j0 = jc * 96 + half * 48;
            __syncthreads();
#pragma unroll
            for (int t = 0; t < 6; ++t) {
                int ix = tid + 256 * t;      // 0..1535
                int jj = ix >> 5, f4 = ix & 31;
                *(float4*)&As[jj * 128 + f4 * 4] =
                    *(const float4*)&a_[(j0 + jj) * 128 + f4 * 4];
            }
#pragma unroll
            for (int t = 0; t < 2; ++t) {
                int ix = tid + 256 * t;
                if (ix < 384) {
                    int jj = ix >> 3, f4 = ix & 7;
                    *(float4*)&Ts[jj * 32 + f4 * 4] =
                        *(const float4*)&tx_[(j0 + jj) * 128 + ot * 32 + f4 * 4];
                }
            }
            __syncthreads();
#pragma unroll 4
            for (int jj = 0; jj < 48; ++jj) {
                float4 av = *(const float4*)&As[jj * 128 + c4 * 4];
                float4 tv = *(const float4*)&Ts[jj * 32 + owt * 4];
                float avv[4] = {av.x, av.y, av.z, av.w};
                float tvv[4] = {tv.x, tv.y, tv.z, tv.w};
#pragma unroll
                for (int oi = 0; oi < 4; ++oi)
#pragma unroll
                    for (int ci = 0; ci < 4; ++ci)
                        accm[oi][ci] += avv[ci] * tvv[oi];
            }
            {   // tsum partial for this half
                const int o = tid & 31, g = tid >> 5;
                float s = 0.0f;
#pragma unroll
                for (int jj = 0; jj < 6; ++jj) s += Ts[(g * 6 + jj) * 32 + o];
                tsacc += s;
            }
        }
#pragma unroll
        for (int oi = 0; oi < 4; ++oi) {
            *(float4*)&Mpart[jc * 16384 + (ot * 32 + owt * 4 + oi) * 128 + c4 * 4] =
                make_float4(accm[oi][0], accm[oi][1], accm[oi][2], accm[oi][3]);
        }
        __syncthreads();
        {
            const int o = tid & 31, g = tid >> 5;
            red[g * 32 + o] = tsacc;
        }
        __syncthreads();
        if (tid < 32) {
            float s = 0.0f;
#pragma unroll
            for (int g = 0; g < 8; ++g) s += red[g * 32 + tid];
            tspart[jc * 128 + ot * 32 + tid] = s;
        }
    }
}

// ---------------------------------------------------------------------------
// ygemmK: 192 blocks: yb = bid/48 (0..3), rt = bid%48 (16-row tiles).
// ---------------------------------------------------------------------------
__global__ __launch_bounds__(256, 4) void ygemmK(
    const float* __restrict__ a_, const float* __restrict__ o_,
    const float* __restrict__ Mpart, const float* __restrict__ lo_w,
    const float* __restrict__ lob, const float* __restrict__ tspart,
    const float* __restrict__ mw, const float* __restrict__ mb,
    const float* __restrict__ xc, float* __restrict__ y1, float* __restrict__ y2)
{
    __shared__ float Bs[64][132];
    const int bid = blockIdx.x;
    const int tid = threadIdx.x;
    const int yb = bid / 48, rt = bid % 48;
    const float* A; float* C; int colbase;
    if (yb < 2) {
        colbase = yb * 64; A = a_; C = y1;
#pragma unroll
        for (int t = 0; t < 8; ++t) {
            int idx = tid + 256 * t;
            int row = idx >> 5, f4 = idx & 31;
            int o = colbase + row;
            float4 s = make_float4(0.f, 0.f, 0.f, 0.f);
#pragma unroll
            for (int jc = 0; jc < 8; ++jc) {
                float4 mv = *(const float4*)&Mpart[jc * 16384 + o * 128 + f4 * 4];
                s.x += mv.x; s.y += mv.y; s.z += mv.z; s.w += mv.w;
            }
            float4 lw4 = *(const float4*)&lo_w[o * 128 + f4 * 4];
            s.x *= lw4.x; s.y *= lw4.y; s.z *= lw4.z; s.w *= lw4.w;
            *(float4*)&Bs[row][f4 * 4] = s;
        }
    } else {
        colbase = (yb - 2) * 64; A = o_; C = y2;
#pragma unroll
        for (int t = 0; t < 8; ++t) {
            int idx = tid + 256 * t;
            int row = idx >> 5, f4 = idx & 31;
            *(float4*)&Bs[row][f4 * 4] =
                *(const float4*)&mw[(colbase + row) * 128 + f4 * 4];
        }
    }
    __syncthreads();
    const int rg = tid >> 4, ng = tid & 15;
    const int r = rt * 16 + rg;
    float accs[4];
#pragma unroll
    for (int c = 0; c < 4; ++c) {
        int gc = colbase + ng + 16 * c;
        float bv;
        if (yb < 2) {
            float s = 0.0f;
#pragma unroll
            for (int jc = 0; jc < 8; ++jc) s += tspart[jc * 128 + gc];
            bv = lob[gc] * s;
        } else {
            bv = mb[gc];
        }
        accs[c] = bv;
    }
    const float* A1 = A + r * 128;
#pragma unroll 8
    for (int kk = 0; kk < 32; ++kk) {
        float4 a1 = *(const float4*)&A1[kk * 4];
#pragma unroll
        for (int c = 0; c < 4; ++c) {
            float4 b = *(const float4*)&Bs[ng + 16 * c][kk * 4];
            accs[c] += a1.x * b.x + a1.y * b.y + a1.z * b.z + a1.w * b.w;
        }
    }
#pragma unroll
    for (int c = 0; c < 4; ++c) {
        int gc = colbase + ng + 16 * c;
        C[r * 128 + gc] = xc[r * 128 + gc] + accs[c];
    }
}

// ---------------------------------------------------------------------------
// finK: out = (x5 + LN(y1) + LN(y2)) @ l1_w^T + l1_b. 96 blocks (16-row).
// ---------------------------------------------------------------------------
__global__ __launch_bounds__(256, 4) void finK(
    const float* __restrict__ xprev, const float* __restrict__ y1,
    const float* __restrict__ y2,
    const float* __restrict__ g1, const float* __restrict__ b1,
    const float* __restrict__ g2, const float* __restrict__ b2,
    const float* __restrict__ w, const float* __restrict__ bias,
    float* __restrict__ outp)
{
    __shared__ float Bs[64][132];
    __shared__ float As[16][132];
    const int bid = blockIdx.x;
    const int tid = threadIdx.x;
    const int ct = bid / 48, rt = bid % 48;
    const int r0 = rt * 16;
    const int colbase = ct * 64;
    stage16(tid, r0, false, false, xprev, y1, y2, g1, b1, g2, b2, nullptr, As);
#pragma unroll
    for (int t = 0; t < 8; ++t) {
        int idx = tid + 256 * t;
        int brow = idx >> 5, f4 = idx & 31;
        *(float4*)&Bs[brow][f4 * 4] = *(const float4*)&w[(colbase + brow) * 128 + f4 * 4];
    }
    __syncthreads();
    const int rg = tid >> 4, ng = tid & 15;
    float accs[4];
#pragma unroll
    for (int c = 0; c < 4; ++c) accs[c] = bias[colbase + ng + 16 * c];
#pragma unroll 8
    for (int kk = 0; kk < 32; ++kk) {
        float4 a1 = *(const float4*)&As[rg][kk * 4];
#pragma unroll
        for (int c = 0; c < 4; ++c) {
            float4 b = *(const float4*)&Bs[ng + 16 * c][kk * 4];
            accs[c] += a1.x * b.x + a1.y * b.y + a1.z * b.z + a1.w * b.w;
        }
    }
    const int r = r0 + rg;
#pragma unroll
    for (int c = 0; c < 4; ++c)
        outp[r * 128 + colbase + ng + 16 * c] = accs[c];
}

// ---------------------------------------------------------------------------
extern "C" void kernel_launch(void* const* d_in, const int* in_sizes, int n_in,
                              void* d_out, int out_size, void* d_ws, size_t ws_size,
                              hipStream_t stream)
{
    const float* x_in      = (const float*)d_in[0];
    const float* cop_l_w   = (const float*)d_in[1];
    const float* cop_l_b   = (const float*)d_in[2];
    const float* cop_lo_w  = (const float*)d_in[3];
    const float* cop_lo_b  = (const float*)d_in[4];
    const float* cop_out_w = (const float*)d_in[5];
    const float* cop_out_b = (const float*)d_in[6];
    const float* cop_ln_g  = (const float*)d_in[7];
    const float* cop_ln_b  = (const float*)d_in[8];
    const float* qkv_w     = (const float*)d_in[9];
    const float* qkv_b     = (const float*)d_in[10];
    const float* mha_out_w = (const float*)d_in[11];
    const float* mha_out_b = (const float*)d_in[12];
    const float* mha_ln_g  = (const float*)d_in[13];
    const float* mha_ln_b  = (const float*)d_in[14];
    const float* l1_w      = (const float*)d_in[15];
    const float* l1_b      = (const float*)d_in[16];

    float* ws = (float*)d_ws;
    float* xA     = ws + 0 * P_SZ;
    float* xB     = ws + 1 * P_SZ;
    float* a_     = ws + 2 * P_SZ;
    float* tx_    = ws + 3 * P_SZ;
    float* y1_    = ws + 4 * P_SZ;
    float* y2_    = ws + 5 * P_SZ;
    float* qkv_   = ws + 6 * P_SZ;          // 3*P_SZ floats
    float* o_     = ws + 9 * P_SZ;
    float* Mpart  = ws + 10 * P_SZ;         // 8 * 16384 floats
    float* tspart = Mpart + 8 * 16384;      // 8 * 128

    const float* xc = x_in;

    for (int i = 0; i < 6; ++i) {
        const float* lw  = cop_l_w   + i * 16384;
        const float* lb  = cop_l_b   + i * 128;
        const float* low = cop_lo_w  + i * 16384;
        const float* lob = cop_lo_b  + i * 128;
        const float* ow  = cop_out_w + i * 16384;
        const float* ob  = cop_out_b + i * 128;
        const float* qw  = qkv_w     + i * 49152;
        const float* qb  = qkv_b     + i * 384;
        const float* mw  = mha_out_w + i * 16384;
        const float* mb  = mha_out_b + i * 128;
        // LN params of the PREVIOUS layer (consumed by the folded combine)
        const float* pg1 = cop_ln_g + (i - 1) * 128;
        const float* pb1 = cop_ln_b + (i - 1) * 128;
        const float* pg2 = mha_ln_g + (i - 1) * 128;
        const float* pb2 = mha_ln_b + (i - 1) * 128;

        if (i == 0) {
            megaK<<<480, 256, 0, stream>>>(1, x_in, nullptr, nullptr, nullptr,
                                           nullptr, nullptr, nullptr, nullptr,
                                           lw, lb, ow, ob, qw, qb, a_, tx_, qkv_);
        } else {
            float* xn = (i & 1) ? xB : xA;
            megaK<<<480, 256, 0, stream>>>(0, xc, y1_, y2_, xn,
                                           pg1, pb1, pg2, pb2,
                                           lw, lb, ow, ob, qw, qb, a_, tx_, qkv_);
            xc = xn;
        }
        k2K<<<416, 256, 0, stream>>>(qkv_, a_, tx_, o_, Mpart, tspart);
        ygemmK<<<192, 256, 0, stream>>>(a_, o_, Mpart, low, lob, tspart, mw, mb,
                                        xc, y1_, y2_);
    }

    finK<<<96, 256, 0, stream>>>(xc, y1_, y2_,
                                 cop_ln_g + 5 * 128, cop_ln_b + 5 * 128,
                                 mha_ln_g + 5 * 128, mha_ln_b + 5 * 128,
                                 l1_w, l1_b, (float*)d_out);
}